// Round 1
// 115.213 us; speedup vs baseline: 1.0794x; 1.0794x over previous
//
#include <hip/hip_runtime.h>
#include <hip/hip_bf16.h>
#include <stdint.h>

#define ALPHA 0.2f

typedef __attribute__((ext_vector_type(8))) short short8;
typedef __attribute__((ext_vector_type(4))) float f32x4;

__device__ inline short f2bf(float x) {
    union { __hip_bfloat16 b; short s; } u;
    u.b = __float2bfloat16(x);
    return u.s;
}

// RNE bf16 truncation for finite, non-NaN inputs (E values are >= 0, finite).
__device__ inline short f2bf_rne(float x) {
    uint32_t u = __float_as_uint(x);
    u += 0x7FFFu + ((u >> 16) & 1u);
    return (short)(u >> 16);
}

__device__ inline void gload16(const short* g, short* l) {
    __builtin_amdgcn_global_load_lds((const __attribute__((address_space(1))) unsigned int*)g,
                                     (__attribute__((address_space(3))) unsigned int*)l, 16, 0, 0);
}

// ---------------- Kernel A: Wh = h@W fp32 (4x4 reg-blocked) + WhT bf16 + f1/f2 + mask-pack ---
// (unchanged — verified)
__global__ __launch_bounds__(256) void kA(const float* __restrict__ h,
                                          const float* __restrict__ W,
                                          const float* __restrict__ av,
                                          const float* __restrict__ adj,
                                          short* __restrict__ whT,
                                          float* __restrict__ f1g,
                                          float* __restrict__ f2g,
                                          uint32_t* __restrict__ maskg) {
    int blk = blockIdx.x;
    int b  = blk >> 6;            // 8 batches
    int n0 = (blk & 63) * 32;     // 64 row-tiles of 32
    __shared__ float hl[32 * 128];
    __shared__ float wh[32 * 132];
    __shared__ float plds[32 * 8 * 2];
    int t = threadIdx.x;

    // folded kM: pack 1 mask word per thread (512 blk * 256 thr == 2048 rows * 64 words)
    {
        int gt = blk * 256 + t;
        int mi = gt >> 6, wd = gt & 63;
        const float* src = adj + (size_t)mi * 2048 + wd * 32;
        uint32_t m = 0;
        #pragma unroll
        for (int k = 0; k < 32; k += 4) {
            f32x4 v = *reinterpret_cast<const f32x4*>(src + k);
            if (v[0] > 0.f) m |= 1u << (k + 0);
            if (v[1] > 0.f) m |= 1u << (k + 1);
            if (v[2] > 0.f) m |= 1u << (k + 2);
            if (v[3] > 0.f) m |= 1u << (k + 3);
        }
        maskg[mi * 64 + wd] = m;
    }

    const f32x4* hs = reinterpret_cast<const f32x4*>(h + ((size_t)(b * 2048 + n0)) * 128);
    f32x4* h4 = reinterpret_cast<f32x4*>(hl);
    #pragma unroll
    for (int k = 0; k < 4; k++) h4[t + k * 256] = hs[t + k * 256];
    __syncthreads();

    int og = t & 31, rg = t >> 5;
    int o0 = og * 4, r0 = rg * 4;
    f32x4 acc0 = {0.f,0.f,0.f,0.f}, acc1 = {0.f,0.f,0.f,0.f};
    f32x4 acc2 = {0.f,0.f,0.f,0.f}, acc3 = {0.f,0.f,0.f,0.f};
    const f32x4* W4  = reinterpret_cast<const f32x4*>(W);
    const f32x4* hv4 = reinterpret_cast<const f32x4*>(hl);
    #pragma unroll 4
    for (int f0 = 0; f0 < 128; f0 += 4) {
        f32x4 h0 = hv4[(r0 + 0) * 32 + (f0 >> 2)];
        f32x4 h1 = hv4[(r0 + 1) * 32 + (f0 >> 2)];
        f32x4 h2 = hv4[(r0 + 2) * 32 + (f0 >> 2)];
        f32x4 h3 = hv4[(r0 + 3) * 32 + (f0 >> 2)];
        f32x4 w0 = W4[(f0 + 0) * 32 + og];
        f32x4 w1 = W4[(f0 + 1) * 32 + og];
        f32x4 w2 = W4[(f0 + 2) * 32 + og];
        f32x4 w3 = W4[(f0 + 3) * 32 + og];
        acc0 += h0[0] * w0 + h0[1] * w1 + h0[2] * w2 + h0[3] * w3;
        acc1 += h1[0] * w0 + h1[1] * w1 + h1[2] * w2 + h1[3] * w3;
        acc2 += h2[0] * w0 + h2[1] * w1 + h2[2] * w2 + h2[3] * w3;
        acc3 += h3[0] * w0 + h3[1] * w1 + h3[2] * w2 + h3[3] * w3;
    }
    *reinterpret_cast<f32x4*>(&wh[(r0 + 0) * 132 + o0]) = acc0;
    *reinterpret_cast<f32x4*>(&wh[(r0 + 1) * 132 + o0]) = acc1;
    *reinterpret_cast<f32x4*>(&wh[(r0 + 2) * 132 + o0]) = acc2;
    *reinterpret_cast<f32x4*>(&wh[(r0 + 3) * 132 + o0]) = acc3;
    __syncthreads();

    {
        int o = t & 127, rg2 = t >> 7;
        short8 lo, hi;
        #pragma unroll
        for (int r = 0; r < 8; r++) lo[r] = f2bf(wh[(rg2 * 16 + r) * 132 + o]);
        #pragma unroll
        for (int r = 0; r < 8; r++) hi[r] = f2bf(wh[(rg2 * 16 + 8 + r) * 132 + o]);
        size_t base = ((size_t)(b * 128 + o)) * 2048 + n0 + rg2 * 16;
        *reinterpret_cast<short8*>(whT + base)     = lo;
        *reinterpret_cast<short8*>(whT + base + 8) = hi;
    }

    {
        int r = t & 31, og8 = t >> 5;
        float s1 = 0.f, s2 = 0.f;
        #pragma unroll
        for (int k = 0; k < 16; k++) {
            float v = wh[r * 132 + og8 * 16 + k];
            s1 += v * av[og8 * 16 + k];
            s2 += v * av[128 + og8 * 16 + k];
        }
        plds[(r * 8 + og8) * 2 + 0] = s1;
        plds[(r * 8 + og8) * 2 + 1] = s2;
    }
    __syncthreads();
    if (t < 64) {
        int r = t & 31, which = t >> 5;
        float s = 0.f;
        #pragma unroll
        for (int og8 = 0; og8 < 8; og8++) s += plds[(r * 8 + og8) * 2 + which];
        if (which == 0) f1g[b * 2048 + n0 + r] = s;
        else            f2g[b * 2048 + n0 + r] = s;
    }
}

// ---------------- Kernel G3: fused E=exp(lrelu(f1+f2))*mask, O=E@Wh^T, out=elu(O/l+bias) ----
// grid 512: (b, 32i-tile). Wave roles (ihalf, kpar): each wave owns a K-parity and the FULL
// o=128 range -> E computed exactly once (no ohalf duplication), 8 MFMA per wave per phase.
// 32 phases of BK=64 (2 K-blocks), 6-deep B-ring (48 KB), counted vmcnt, one barrier/phase.
__global__ __launch_bounds__(256) void kG3(const uint32_t* __restrict__ maskg,
                                           const short* __restrict__ whT,
                                           const float* __restrict__ f1g,
                                           const float* __restrict__ f2g,
                                           const float* __restrict__ bias,
                                           float* __restrict__ out) {
    int blk = blockIdx.x;
    int b      = blk >> 6;
    int i_tile = (blk & 63) * 32;
    int t = threadIdx.x;
    int w = t >> 6, lane = t & 63, il = lane & 15, quad = lane >> 4;
    int ihalf = w & 1, kpar = w >> 1;
    int i_base = i_tile + ihalf * 16;

    __shared__ uint32_t m32l[32 * 68];   // stride 68: 2-way conflict max (free, m136)
    __shared__ float    f2l[2048];
    __shared__ short    Bl[6 * 4096];    // 48 KB, 6-deep ring of 8 KB B-tiles
    __shared__ float    lred[32 * 8];
    __shared__ float    linvl[32];

    // extras first (oldest in vmcnt queue; their ds_writes force their drain pre-loop)
    float f1v = f1g[b * 2048 + i_base + il];
    const uint4* msrc = reinterpret_cast<const uint4*>(maskg + (size_t)i_tile * 64);
    uint4 mv0 = msrc[t];
    uint4 mv1 = msrc[t + 256];
    const f32x4* fsrc = reinterpret_cast<const f32x4*>(f2g + b * 2048);
    f32x4 fv0 = fsrc[t];
    f32x4 fv1 = fsrc[t + 256];

    {
        int row0 = t >> 4, wq0 = (t & 15) * 4;
        *reinterpret_cast<uint4*>(&m32l[row0 * 68 + wq0]) = mv0;
        int idx = t + 256;
        int row1 = idx >> 4, wq1 = (idx & 15) * 4;
        *reinterpret_cast<uint4*>(&m32l[row1 * 68 + wq1]) = mv1;
        f32x4* fdst = reinterpret_cast<f32x4*>(f2l);
        fdst[t]       = fv0;
        fdst[t + 256] = fv1;
    }

    // B staging geometry (swizzled, verified)
    int r = t >> 2, cs = t & 3;
    int rB1 = r + 64;
    const short* gB0 = whT + ((size_t)(b * 128 + r))   * 2048 + ((cs ^ ((r   >> 1) & 3)) << 3);
    const short* gB1 = whT + ((size_t)(b * 128 + rB1)) * 2048 + ((cs ^ ((rB1 >> 1) & 3)) << 3);
    int lslot = t * 8;

#define STAGEB(KB, SL) do {                                                      \
    gload16(gB0 + (KB) * 32, &Bl[(SL) * 4096 + lslot]);                          \
    gload16(gB1 + (KB) * 32, &Bl[(SL) * 4096 + 2048 + lslot]);                   \
} while (0)

    // prologue: stage K-blocks 0..3 into slots 0..3 (8 gloads/thread in flight)
    STAGEB(0, 0); STAGEB(1, 1); STAGEB(2, 2); STAGEB(3, 3);

    int sw = (quad ^ ((il >> 1) & 3)) << 3;
    int mrow = (ihalf * 16 + il) * 68;
    int qsh = quad * 8;

    f32x4 acc[8] = {{0.f,0.f,0.f,0.f},{0.f,0.f,0.f,0.f},{0.f,0.f,0.f,0.f},{0.f,0.f,0.f,0.f},
                    {0.f,0.f,0.f,0.f},{0.f,0.f,0.f,0.f},{0.f,0.f,0.f,0.f},{0.f,0.f,0.f,0.f}};
    float lpart = 0.f;

    // barrier covering mask/f2 LDS stores; leaves ring gloads in flight (lgkm only)
    __asm__ __volatile__("" ::: "memory");
    __builtin_amdgcn_s_waitcnt(0xC07F);   // lgkmcnt(0)
    __builtin_amdgcn_s_barrier();
    __asm__ __volatile__("" ::: "memory");

// One phase = this wave's K-block (KB = 2p + kpar) from ring slot SL.
// vmcnt(WAITN) before barrier: ensures KB 2p AND 2p+1 are resident (oldest-first FIFO).
#define PHASE(KB, SL, WAITN, ST, KS0, SS0, KS1, SS1) do {                        \
    __asm__ __volatile__("" ::: "memory");                                       \
    __builtin_amdgcn_s_waitcnt(0x0F70 | (WAITN));  /* vmcnt(WAITN) */            \
    __builtin_amdgcn_s_barrier();                                                \
    __asm__ __volatile__("" ::: "memory");                                       \
    if (ST) { STAGEB(KS0, SS0); STAGEB(KS1, SS1); }                              \
    uint32_t mq = m32l[mrow + (KB)] >> qsh;                                      \
    f32x4 q0 = *reinterpret_cast<const f32x4*>(&f2l[(KB) * 32 + quad * 8]);      \
    f32x4 q1 = *reinterpret_cast<const f32x4*>(&f2l[(KB) * 32 + quad * 8 + 4]);  \
    short8 af; float esum = 0.f;                                                 \
    _Pragma("unroll")                                                            \
    for (int k = 0; k < 8; k++) {                                                \
        float x = f1v + ((k < 4) ? q0[k] : q1[k - 4]);                           \
        x = fmaxf(x, ALPHA * x);                                                 \
        float e = ((mq >> k) & 1u) ? __expf(x) : 0.f;                            \
        af[k] = f2bf_rne(e); esum += e;                                          \
    }                                                                            \
    lpart += esum;                                                               \
    const short* Bb = &Bl[(SL) * 4096];                                          \
    _Pragma("unroll")                                                            \
    for (int q = 0; q < 8; q++) {                                                \
        short8 bq = *reinterpret_cast<const short8*>(Bb + (q * 16 + il) * 32 + sw); \
        acc[q] = __builtin_amdgcn_mfma_f32_16x16x32_bf16(af, bq, acc[q], 0, 0, 0);  \
    }                                                                            \
} while (0)

    // slot pattern has period 3 phases (6 K-blocks); stage-ahead = 4 K-blocks.
    for (int p = 0; p < 30; p += 3) {
        int K0 = 2 * p;
        PHASE(K0     + kpar, 0 + kpar, 4, 1, K0 + 4, 4, K0 + 5, 5);
        PHASE(K0 + 2 + kpar, 2 + kpar, 4, 1, K0 + 6, 0, K0 + 7, 1);
        PHASE(K0 + 4 + kpar, 4 + kpar, 4, 1, K0 + 8, 2, K0 + 9, 3);
    }
    PHASE(60 + kpar, 0 + kpar, 4, 0, 0, 0, 0, 0);   // KB 62,63 still in flight
    PHASE(62 + kpar, 2 + kpar, 0, 0, 0, 0, 0, 0);   // drain
#undef PHASE
#undef STAGEB

    // row-sum reduction: each lane owns a distinct (row, kpar, quad) partial
    lred[(ihalf * 16 + il) * 8 + kpar * 4 + quad] = lpart;
    __syncthreads();
    if (t < 32) {
        const float* lr = &lred[t * 8];
        linvl[t] = 1.f / (lr[0] + lr[1] + lr[2] + lr[3] + lr[4] + lr[5] + lr[6] + lr[7]);
    }
    // merge kpar accumulators via LDS scratch (reuses ring slots 0-1; main-loop reads done)
    f32x4* sc = reinterpret_cast<f32x4*>(Bl);
    if (kpar == 1) {
        #pragma unroll
        for (int q = 0; q < 8; q++) sc[(ihalf * 64 + lane) * 8 + q] = acc[q];
    }
    __syncthreads();

    if (kpar == 0) {
        #pragma unroll
        for (int q = 0; q < 8; q++) {
            f32x4 oacc = acc[q] + sc[(ihalf * 64 + lane) * 8 + q];
            int oo = q * 16 + il;
            float bv = bias[oo];
            #pragma unroll
            for (int rr = 0; rr < 4; rr++) {
                int irel = ihalf * 16 + quad * 4 + rr;
                float v = oacc[rr] * linvl[irel] + bv;
                int ii = i_tile + irel;
                out[((size_t)(b * 2048 + ii)) * 128 + oo] = v > 0.f ? v : (__expf(v) - 1.f);
            }
        }
    }
}

extern "C" void kernel_launch(void* const* d_in, const int* in_sizes, int n_in,
                              void* d_out, int out_size, void* d_ws, size_t ws_size,
                              hipStream_t stream) {
    const float* h    = (const float*)d_in[0];
    const float* adj  = (const float*)d_in[1];
    const float* W    = (const float*)d_in[2];
    const float* av   = (const float*)d_in[3];
    const float* bias = (const float*)d_in[4];
    float* out = (float*)d_out;

    char* ws = (char*)d_ws;
    short*    whT   = (short*)ws;                       // 4 MB
    float*    f1g   = (float*)(ws + (4 << 20));         // 64 KB
    float*    f2g   = f1g + 16384;                      // 64 KB
    uint32_t* maskg = (uint32_t*)(ws + (5 << 20));      // 512 KB

    kA<<<512, 256, 0, stream>>>(h, W, av, adj, whT, f1g, f2g, maskg);
    kG3<<<512, 256, 0, stream>>>(maskg, whT, f1g, f2g, bias, out);
}

// Round 2
// 111.389 us; speedup vs baseline: 1.1165x; 1.0343x over previous
//
#include <hip/hip_runtime.h>
#include <hip/hip_bf16.h>
#include <stdint.h>

#define ALPHA 0.2f

typedef __attribute__((ext_vector_type(8))) short short8;
typedef __attribute__((ext_vector_type(4))) float f32x4;

__device__ inline short f2bf(float x) {
    union { __hip_bfloat16 b; short s; } u;
    u.b = __float2bfloat16(x);
    return u.s;
}

// RNE bf16 truncation for finite, non-NaN inputs (E values are >= 0, finite).
__device__ inline short f2bf_rne(float x) {
    uint32_t u = __float_as_uint(x);
    u += 0x7FFFu + ((u >> 16) & 1u);
    return (short)(u >> 16);
}

__device__ inline void gload16(const short* g, short* l) {
    __builtin_amdgcn_global_load_lds((const __attribute__((address_space(1))) unsigned int*)g,
                                     (__attribute__((address_space(3))) unsigned int*)l, 16, 0, 0);
}

// ---------------- Kernel A: Wh = h@W fp32 (4x4 reg-blocked) + WhT bf16 + f1/f2 + mask-pack ---
// (unchanged — verified)
__global__ __launch_bounds__(256) void kA(const float* __restrict__ h,
                                          const float* __restrict__ W,
                                          const float* __restrict__ av,
                                          const float* __restrict__ adj,
                                          short* __restrict__ whT,
                                          float* __restrict__ f1g,
                                          float* __restrict__ f2g,
                                          uint32_t* __restrict__ maskg) {
    int blk = blockIdx.x;
    int b  = blk >> 6;            // 8 batches
    int n0 = (blk & 63) * 32;     // 64 row-tiles of 32
    __shared__ float hl[32 * 128];
    __shared__ float wh[32 * 132];
    __shared__ float plds[32 * 8 * 2];
    int t = threadIdx.x;

    // folded kM: pack 1 mask word per thread (512 blk * 256 thr == 2048 rows * 64 words)
    {
        int gt = blk * 256 + t;
        int mi = gt >> 6, wd = gt & 63;
        const float* src = adj + (size_t)mi * 2048 + wd * 32;
        uint32_t m = 0;
        #pragma unroll
        for (int k = 0; k < 32; k += 4) {
            f32x4 v = *reinterpret_cast<const f32x4*>(src + k);
            if (v[0] > 0.f) m |= 1u << (k + 0);
            if (v[1] > 0.f) m |= 1u << (k + 1);
            if (v[2] > 0.f) m |= 1u << (k + 2);
            if (v[3] > 0.f) m |= 1u << (k + 3);
        }
        maskg[mi * 64 + wd] = m;
    }

    const f32x4* hs = reinterpret_cast<const f32x4*>(h + ((size_t)(b * 2048 + n0)) * 128);
    f32x4* h4 = reinterpret_cast<f32x4*>(hl);
    #pragma unroll
    for (int k = 0; k < 4; k++) h4[t + k * 256] = hs[t + k * 256];
    __syncthreads();

    int og = t & 31, rg = t >> 5;
    int o0 = og * 4, r0 = rg * 4;
    f32x4 acc0 = {0.f,0.f,0.f,0.f}, acc1 = {0.f,0.f,0.f,0.f};
    f32x4 acc2 = {0.f,0.f,0.f,0.f}, acc3 = {0.f,0.f,0.f,0.f};
    const f32x4* W4  = reinterpret_cast<const f32x4*>(W);
    const f32x4* hv4 = reinterpret_cast<const f32x4*>(hl);
    #pragma unroll 4
    for (int f0 = 0; f0 < 128; f0 += 4) {
        f32x4 h0 = hv4[(r0 + 0) * 32 + (f0 >> 2)];
        f32x4 h1 = hv4[(r0 + 1) * 32 + (f0 >> 2)];
        f32x4 h2 = hv4[(r0 + 2) * 32 + (f0 >> 2)];
        f32x4 h3 = hv4[(r0 + 3) * 32 + (f0 >> 2)];
        f32x4 w0 = W4[(f0 + 0) * 32 + og];
        f32x4 w1 = W4[(f0 + 1) * 32 + og];
        f32x4 w2 = W4[(f0 + 2) * 32 + og];
        f32x4 w3 = W4[(f0 + 3) * 32 + og];
        acc0 += h0[0] * w0 + h0[1] * w1 + h0[2] * w2 + h0[3] * w3;
        acc1 += h1[0] * w0 + h1[1] * w1 + h1[2] * w2 + h1[3] * w3;
        acc2 += h2[0] * w0 + h2[1] * w1 + h2[2] * w2 + h2[3] * w3;
        acc3 += h3[0] * w0 + h3[1] * w1 + h3[2] * w2 + h3[3] * w3;
    }
    *reinterpret_cast<f32x4*>(&wh[(r0 + 0) * 132 + o0]) = acc0;
    *reinterpret_cast<f32x4*>(&wh[(r0 + 1) * 132 + o0]) = acc1;
    *reinterpret_cast<f32x4*>(&wh[(r0 + 2) * 132 + o0]) = acc2;
    *reinterpret_cast<f32x4*>(&wh[(r0 + 3) * 132 + o0]) = acc3;
    __syncthreads();

    {
        int o = t & 127, rg2 = t >> 7;
        short8 lo, hi;
        #pragma unroll
        for (int r = 0; r < 8; r++) lo[r] = f2bf(wh[(rg2 * 16 + r) * 132 + o]);
        #pragma unroll
        for (int r = 0; r < 8; r++) hi[r] = f2bf(wh[(rg2 * 16 + 8 + r) * 132 + o]);
        size_t base = ((size_t)(b * 128 + o)) * 2048 + n0 + rg2 * 16;
        *reinterpret_cast<short8*>(whT + base)     = lo;
        *reinterpret_cast<short8*>(whT + base + 8) = hi;
    }

    {
        int r = t & 31, og8 = t >> 5;
        float s1 = 0.f, s2 = 0.f;
        #pragma unroll
        for (int k = 0; k < 16; k++) {
            float v = wh[r * 132 + og8 * 16 + k];
            s1 += v * av[og8 * 16 + k];
            s2 += v * av[128 + og8 * 16 + k];
        }
        plds[(r * 8 + og8) * 2 + 0] = s1;
        plds[(r * 8 + og8) * 2 + 1] = s2;
    }
    __syncthreads();
    if (t < 64) {
        int r = t & 31, which = t >> 5;
        float s = 0.f;
        #pragma unroll
        for (int og8 = 0; og8 < 8; og8++) s += plds[(r * 8 + og8) * 2 + which];
        if (which == 0) f1g[b * 2048 + n0 + r] = s;
        else            f2g[b * 2048 + n0 + r] = s;
    }
}

// ---------------- Kernel G4: fused E=exp(lrelu(f1+f2))*mask, O=E@Wh^T, out=elu(O/l+bias) ----
// i_tile=64, 512 threads, 8 waves = (rowgroup 0..3) x (kpar 0..1). grid 256 = 1 block/CU.
// b = blk&7: round-robin block->XCD dispatch pins each batch to one XCD -> whT panel
// (512 KB) becomes L2-resident -> B-traffic drops 268 MB(L3) -> ~L2 hits.
// 32 phases of BK=64 (2 K-blocks/phase), 8-deep B-ring (64 KB), counted vmcnt(4).
__global__ __launch_bounds__(512) void kG4(const uint32_t* __restrict__ maskg,
                                           const short* __restrict__ whT,
                                           const float* __restrict__ f1g,
                                           const float* __restrict__ f2g,
                                           const float* __restrict__ bias,
                                           float* __restrict__ out) {
    int blk = blockIdx.x;
    int b      = blk & 7;             // XCD-pin: all 32 blocks of batch b -> same XCD
    int i_tile = (blk >> 3) * 64;
    int t = threadIdx.x;
    int w = t >> 6, lane = t & 63, il = lane & 15, quad = lane >> 4;
    int rg = w & 3, kpar = w >> 2;

    __shared__ uint32_t m32l[64 * 68];   // 17.4 KB, stride 68: 2-way conflict max (free)
    __shared__ float    f2l[2048];       // 8 KB
    __shared__ short    Bl[8 * 4096];    // 64 KB, 8-deep ring of 8 KB B-tiles
    __shared__ float    lred[64 * 8];    // 2 KB
    __shared__ float    linvl[64];

    // extras first (oldest in vmcnt queue; compiler's waits for them don't drain ring gloads)
    float f1v = f1g[b * 2048 + i_tile + rg * 16 + il];
    const uint4* msrc = reinterpret_cast<const uint4*>(maskg + (size_t)i_tile * 64);
    uint4 mv0 = msrc[t];
    uint4 mv1 = msrc[t + 512];
    const f32x4* fsrc = reinterpret_cast<const f32x4*>(f2g + b * 2048);
    f32x4 fv0 = fsrc[t];

    {
        int row0 = t >> 4, wq0 = (t & 15) * 4;
        *reinterpret_cast<uint4*>(&m32l[row0 * 68 + wq0]) = mv0;
        int idx = t + 512;
        int row1 = idx >> 4, wq1 = (idx & 15) * 4;
        *reinterpret_cast<uint4*>(&m32l[row1 * 68 + wq1]) = mv1;
        reinterpret_cast<f32x4*>(f2l)[t] = fv0;
    }

    // B staging geometry: 512 threads x 16B = one full 8 KB tile per STAGEB (swizzled)
    int r = t >> 2, cs = t & 3;
    const short* gB = whT + ((size_t)(b * 128 + r)) * 2048 + ((cs ^ ((r >> 1) & 3)) << 3);
    int lslot = t * 8;

#define STAGEB(KB, SL) gload16(gB + (KB) * 32, &Bl[(SL) * 4096 + lslot])

    // prologue: stage K-blocks 0..5 into slots 0..5 (6 gloads/thread in flight)
    STAGEB(0, 0); STAGEB(1, 1); STAGEB(2, 2); STAGEB(3, 3); STAGEB(4, 4); STAGEB(5, 5);

    int sw = (quad ^ ((il >> 1) & 3)) << 3;
    int mrow = (rg * 16 + il) * 68;
    int qsh = quad * 8;

    f32x4 acc[8] = {{0.f,0.f,0.f,0.f},{0.f,0.f,0.f,0.f},{0.f,0.f,0.f,0.f},{0.f,0.f,0.f,0.f},
                    {0.f,0.f,0.f,0.f},{0.f,0.f,0.f,0.f},{0.f,0.f,0.f,0.f},{0.f,0.f,0.f,0.f}};
    float lpart = 0.f;

    // barrier covering mask/f2 LDS stores; leaves ring gloads in flight (lgkm only)
    __asm__ __volatile__("" ::: "memory");
    __builtin_amdgcn_s_waitcnt(0xC07F);   // lgkmcnt(0)
    __builtin_amdgcn_s_barrier();
    __asm__ __volatile__("" ::: "memory");

// Phase P (0..31): this wave computes KB = 2P+kpar from ring slot (J2+kpar), J2 = (2P)&7.
// vmcnt(WAITN) before barrier ensures KB 2P,2P+1 resident (FIFO, 1 gload/thread/KB).
#define PHASE(P, J2, WAITN, ST) do {                                             \
    __asm__ __volatile__("" ::: "memory");                                       \
    __builtin_amdgcn_s_waitcnt(0x0F70 | (WAITN));  /* vmcnt(WAITN) */            \
    __builtin_amdgcn_s_barrier();                                                \
    __asm__ __volatile__("" ::: "memory");                                       \
    if (ST) { STAGEB(2 * (P) + 6, ((J2) + 6) & 7);                               \
              STAGEB(2 * (P) + 7, ((J2) + 7) & 7); }                             \
    int KB = 2 * (P) + kpar;                                                     \
    uint32_t mq = m32l[mrow + KB] >> qsh;                                        \
    f32x4 q0 = *reinterpret_cast<const f32x4*>(&f2l[KB * 32 + quad * 8]);        \
    f32x4 q1 = *reinterpret_cast<const f32x4*>(&f2l[KB * 32 + quad * 8 + 4]);    \
    short8 af; float esum = 0.f;                                                 \
    _Pragma("unroll")                                                            \
    for (int k = 0; k < 8; k++) {                                                \
        float x = f1v + ((k < 4) ? q0[k] : q1[k - 4]);                           \
        x = fmaxf(x, ALPHA * x);                                                 \
        float e = ((mq >> k) & 1u) ? __expf(x) : 0.f;                            \
        af[k] = f2bf_rne(e); esum += e;                                          \
    }                                                                            \
    lpart += esum;                                                               \
    const short* Bb = &Bl[((J2) + kpar) * 4096];                                 \
    _Pragma("unroll")                                                            \
    for (int q = 0; q < 8; q++) {                                                \
        short8 bq = *reinterpret_cast<const short8*>(Bb + (q * 16 + il) * 32 + sw); \
        acc[q] = __builtin_amdgcn_mfma_f32_16x16x32_bf16(af, bq, acc[q], 0, 0, 0);  \
    }                                                                            \
} while (0)

    // slot pattern period = 4 phases (8 K-blocks, 8 slots); stage-ahead = 3 phases.
    for (int po = 0; po < 28; po += 4) {
        PHASE(po + 0, 0, 4, 1);
        PHASE(po + 1, 2, 4, 1);
        PHASE(po + 2, 4, 4, 1);
        PHASE(po + 3, 6, 4, 1);
    }
    PHASE(28, 0, 4, 1);   // stages KB 62,63 (last)
    PHASE(29, 2, 4, 0);
    PHASE(30, 4, 2, 0);
    PHASE(31, 6, 0, 0);
#undef PHASE
#undef STAGEB

    // row-sum reduction: each lane owns a distinct (row, kpar, quad) partial
    lred[(rg * 16 + il) * 8 + kpar * 4 + quad] = lpart;
    __syncthreads();
    if (t < 64) {
        const float* lr = &lred[t * 8];
        linvl[t] = 1.f / (lr[0] + lr[1] + lr[2] + lr[3] + lr[4] + lr[5] + lr[6] + lr[7]);
    }
    // merge kpar accumulators via LDS scratch (reuses ring; q-slot xor-swizzled vs lane
    // to avoid all-lanes-same-bank on the 128B-stride b128 stores)
    f32x4* sc = reinterpret_cast<f32x4*>(Bl);
    if (kpar == 1) {
        #pragma unroll
        for (int q = 0; q < 8; q++) sc[(rg * 64 + lane) * 8 + (q ^ (lane & 7))] = acc[q];
    }
    __syncthreads();

    if (kpar == 0) {
        #pragma unroll
        for (int q = 0; q < 8; q++) {
            f32x4 oacc = acc[q] + sc[(rg * 64 + lane) * 8 + (q ^ (lane & 7))];
            int oo = q * 16 + il;
            float bv = bias[oo];
            #pragma unroll
            for (int rr = 0; rr < 4; rr++) {
                int irel = rg * 16 + quad * 4 + rr;
                float v = oacc[rr] * linvl[irel] + bv;
                int ii = i_tile + irel;
                out[((size_t)(b * 2048 + ii)) * 128 + oo] = v > 0.f ? v : (__expf(v) - 1.f);
            }
        }
    }
}

extern "C" void kernel_launch(void* const* d_in, const int* in_sizes, int n_in,
                              void* d_out, int out_size, void* d_ws, size_t ws_size,
                              hipStream_t stream) {
    const float* h    = (const float*)d_in[0];
    const float* adj  = (const float*)d_in[1];
    const float* W    = (const float*)d_in[2];
    const float* av   = (const float*)d_in[3];
    const float* bias = (const float*)d_in[4];
    float* out = (float*)d_out;

    char* ws = (char*)d_ws;
    short*    whT   = (short*)ws;                       // 4 MB
    float*    f1g   = (float*)(ws + (4 << 20));         // 64 KB
    float*    f2g   = f1g + 16384;                      // 64 KB
    uint32_t* maskg = (uint32_t*)(ws + (5 << 20));      // 512 KB

    kA<<<512, 256, 0, stream>>>(h, W, av, adj, whT, f1g, f2g, maskg);
    kG4<<<256, 512, 0, stream>>>(maskg, whT, f1g, f2g, bias, out);
}